// Round 8
// baseline (373.954 us; speedup 1.0000x reference)
//
#include <hip/hip_runtime.h>

#define SEQ 512
#define BATCH 1024
#define NT 64
#define BT (BATCH * NT)        // float stride between timesteps in emissions
#define GC 32                  // chains per group (one wave)
#define NGROUP (BATCH / GC)    // 32 denominator blocks
#define NUMER_BLOCKS 512
#define LN2F 0.69314718055994531f
#define LOG2E 1.44269504088896340f

typedef __attribute__((ext_vector_type(8))) short short8;
typedef __attribute__((ext_vector_type(16))) float f32x16;
typedef __attribute__((ext_vector_type(4))) unsigned u32x4;

__device__ __forceinline__ unsigned cvt_pk_bf16(float lo, float hi) {
    unsigned r;
    asm("v_cvt_pk_bf16_f32 %0, %1, %2" : "=v"(r) : "v"(lo), "v"(hi));
    return r;
}
__device__ __forceinline__ float vexp2(float x) {   // 2^x, native
    float r;
    asm("v_exp_f32 %0, %1" : "=v"(r) : "v"(x));
    return r;
}
__device__ __forceinline__ short8 mk8(unsigned a, unsigned b, unsigned c, unsigned d) {
    u32x4 t = {a, b, c, d};
    return __builtin_bit_cast(short8, t);
}

// Forward algorithm, 32 chains/wave, mfma_f32_32x32x16_bf16, turnaround via
// permlane32_swap (no LDS on the critical path). Emissions staged global->LDS
// in 4-step chunks, XOR-swizzled source so ds_read_b128 is conflict-free.
__global__ __launch_bounds__(64, 1) void crf_fused(
    const float* __restrict__ em, const int* __restrict__ tags,
    const int* __restrict__ lens, const float* __restrict__ st,
    const float* __restrict__ en, const float* __restrict__ tr,
    float* __restrict__ out)
{
    __shared__ __align__(16) float em_lds[2][4][GC][NT];   // 64 KB
    const int lane = threadIdx.x;
    const int n = lane & 31;       // chain within group / MFMA col
    const int g = lane >> 5;       // half (0/1)

    if (blockIdx.x < NGROUP) {
        const int cb = blockIdx.x * GC;
        const int Lc = lens[cb + n];

        // ---- A-frags: E^T, slot (t, f, g, j): m = n + 32t, k = 16f + 8g + j ----
        unsigned Au[2][4][4];
        #pragma unroll
        for (int t = 0; t < 2; ++t)
            #pragma unroll
            for (int f = 0; f < 4; ++f)
                #pragma unroll
                for (int j2 = 0; j2 < 4; ++j2) {
                    int k = 16 * f + 8 * g + 2 * j2;
                    int m = n + 32 * t;
                    Au[t][f][j2] = cvt_pk_bf16(__expf(tr[k * NT + m]),
                                               __expf(tr[(k + 1) * NT + m]));
                }

        // ---- B init: p0[k] = exp(st[k] + em0[k] - xs), xs = st[0] + em0[0] ----
        const float xs = st[0] + em[(size_t)(cb + n) * NT];
        unsigned Bu[4][4];
        #pragma unroll
        for (int f = 0; f < 4; ++f)
            #pragma unroll
            for (int j2 = 0; j2 < 4; ++j2) {
                int k = 16 * f + 8 * g + 2 * j2;
                float p0 = __expf(st[k]     + em[(size_t)(cb + n) * NT + k]     - xs);
                float p1 = __expf(st[k + 1] + em[(size_t)(cb + n) * NT + k + 1] - xs);
                Bu[f][j2] = cvt_pk_bf16(p0, p1);
            }

        // ---- staging: chunk = 4 steps; source pre-swizzled (XOR granule) ----
        // LDS slot [GC][NT]: chain row n, 16B granule r' holds source granule
        // r' ^ (n & 7).  Writes linear (global_load_lds), reads swizzled.
        const int colp0 = 4 * ((lane & 15) ^ ((lane >> 4)));        // i even: n&7 = lane>>4
        const int colp1 = 4 * ((lane & 15) ^ ((lane >> 4) + 4));    // i odd:  n&7 = 4 + lane>>4
        auto stage = [&](int ch) {
            const int buf = ch & 1;
            #pragma unroll
            for (int slot = 0; slot < 4; ++slot)
                #pragma unroll
                for (int i = 0; i < 8; ++i) {
                    const float* gsrc = em + (size_t)(ch * 4 + slot) * BT
                                        + (size_t)(cb + 4 * i + (lane >> 4)) * NT
                                        + ((i & 1) ? colp1 : colp0);
                    __builtin_amdgcn_global_load_lds(
                        (const __attribute__((address_space(1))) void*)gsrc,
                        (__attribute__((address_space(3))) void*)&em_lds[buf][slot][4 * i][0],
                        16, 0, 0);
                }
        };

        // per-lane read offsets (words): (t,q) -> n*64 + ((8t+2q+g)^(n&7))*4
        int rdoff[8];
        #pragma unroll
        for (int t = 0; t < 2; ++t)
            #pragma unroll
            for (int q = 0; q < 4; ++q)
                rdoff[4 * t + q] = n * NT + (((8 * t + 2 * q + g) ^ (n & 7)) << 2);
        const float* lds_flat = &em_lds[0][0][0][0];

        stage(0);
        asm volatile("s_waitcnt vmcnt(0)" ::: "memory");
        stage(1);

        int ksum = 0, pend_k = 0;
        float nkf = 0.f;   // -(float)pend_k

        for (int s = 1; s < SEQ; ++s) {
            if ((s & 3) == 0) {
                asm volatile("s_waitcnt vmcnt(0)" ::: "memory");
                int nc = (s >> 2) + 1;
                if (nc < SEQ / 4) stage(nc);
            }

            // ---- 8x MFMA: acc[t] = E^T-tile-t x P  (K=64 as 4 frags) ----
            f32x16 acc0, acc1;
            #pragma unroll
            for (int i = 0; i < 16; ++i) { acc0[i] = 0.f; acc1[i] = 0.f; }
            #pragma unroll
            for (int f = 0; f < 4; ++f) {
                short8 Bf = mk8(Bu[f][0], Bu[f][1], Bu[f][2], Bu[f][3]);
                acc0 = __builtin_amdgcn_mfma_f32_32x32x16_bf16(
                    mk8(Au[0][f][0], Au[0][f][1], Au[0][f][2], Au[0][f][3]), Bf, acc0, 0, 0, 0);
                acc1 = __builtin_amdgcn_mfma_f32_32x32x16_bf16(
                    mk8(Au[1][f][0], Au[1][f][1], Au[1][f][2], Au[1][f][3]), Bf, acc1, 0, 0, 0);
            }

            // ---- epilogue: y = acc * 2^(em*log2e - pend_k); pack pairs ----
            const int soff = (s & 7) << 11;       // slot word base
            unsigned pk[2][8];
            #pragma unroll
            for (int t = 0; t < 2; ++t) {
                #pragma unroll
                for (int q = 0; q < 4; ++q) {
                    float4 e4 = *(const float4*)(lds_flat + soff + rdoff[4 * t + q]);
                    const f32x16& ac = t ? acc1 : acc0;
                    float y0 = ac[4 * q + 0] * vexp2(fmaf(e4.x, LOG2E, nkf));
                    float y1 = ac[4 * q + 1] * vexp2(fmaf(e4.y, LOG2E, nkf));
                    float y2 = ac[4 * q + 2] * vexp2(fmaf(e4.z, LOG2E, nkf));
                    float y3 = ac[4 * q + 3] * vexp2(fmaf(e4.w, LOG2E, nkf));
                    pk[t][2 * q]     = cvt_pk_bf16(y0, y1);
                    pk[t][2 * q + 1] = cvt_pk_bf16(y2, y3);
                }
            }

            // ---- rep (chain state-0, g=0 half's pk[0][0] low word) to all lanes.
            // swap(ra, rb) with distinct regs (forced via opaque mov so the
            // allocator cannot coalesce): ra' = x[lane&31] for ALL lanes —
            // the g=0 half broadcast. R7 BUG was selecting rb for lanes<32
            // (= g=1 half, state 4) -> halves applied different scales.
            unsigned ra = pk[0][0];
            unsigned rb;
            asm("v_mov_b32 %0, %1" : "=v"(rb) : "v"(ra));
            asm("v_permlane32_swap_b32 %0, %1" : "+v"(ra), "+v"(rb));
            unsigned rep_u = ra;

            const bool live = (s < Lc);
            if (live) ksum += pend_k;

            // ---- turnaround: post-swap registers ARE the B-frag words ----
            #pragma unroll
            for (int f = 0; f < 4; ++f) {
                const int t = f >> 1, i0 = 4 * (f & 1);
                unsigned x0 = pk[t][i0],     y0 = pk[t][i0 + 2];
                unsigned x1 = pk[t][i0 + 1], y1 = pk[t][i0 + 3];
                asm("v_permlane32_swap_b32 %0, %1" : "+v"(x0), "+v"(y0));
                asm("v_permlane32_swap_b32 %0, %1" : "+v"(x1), "+v"(y1));
                Bu[f][0] = live ? x0 : Bu[f][0];
                Bu[f][1] = live ? x1 : Bu[f][1];
                Bu[f][2] = live ? y0 : Bu[f][2];
                Bu[f][3] = live ? y1 : Bu[f][3];
            }

            // ---- next-step scale from bf16 exponent of rep (stale-by-one) ----
            int kk = (int)((rep_u >> 7) & 255) - 127;
            kk = kk < -30 ? -30 : (kk > 30 ? 30 : kk);
            pend_k = kk;
            nkf = -(float)kk;
        }

        // ---- final: denom_n = xs + ksum*ln2 + log(sum_k p[k] * exp(en[k])) ----
        float part = 0.f;
        #pragma unroll
        for (int f = 0; f < 4; ++f)
            #pragma unroll
            for (int j2 = 0; j2 < 4; ++j2) {
                unsigned u = Bu[f][j2];
                int k0 = 16 * f + 8 * g + 2 * j2;
                part += __uint_as_float(u << 16)         * __expf(en[k0]);
                part += __uint_as_float(u & 0xffff0000u) * __expf(en[k0 + 1]);
            }
        part += __shfl_xor(part, 32);
        part = fmaxf(part, 1e-35f);
        if (lane < 32)
            atomicAdd(out, -(xs + (float)ksum * LN2F + __logf(part)));
    } else {
        // ---------------- numerator: tag-path score (grid-stride gather) -------
        const int t0 = (blockIdx.x - NGROUP) * 64 + lane;
        float acc = 0.f;
        for (int idx = t0; idx < SEQ * BATCH; idx += NUMER_BLOCKS * 64) {
            int b = idx & (BATCH - 1);
            int s = idx >> 10;
            int L = lens[b];
            int tg = tags[s * BATCH + b];
            float v = 0.f;
            if (s == 0) {
                v = st[tg] + em[(size_t)b * NT + tg];
            } else if (s < L) {
                int tp = tags[(s - 1) * BATCH + b];
                v = tr[tp * NT + tg] + em[(size_t)s * BT + (size_t)b * NT + tg];
            }
            if (s == L - 1) v += en[tg];
            acc += v;
        }
        #pragma unroll
        for (int d = 32; d > 0; d >>= 1) acc += __shfl_xor(acc, d);
        if (lane == 0) atomicAdd(out, acc);
    }
}

extern "C" void kernel_launch(void* const* d_in, const int* in_sizes, int n_in,
                              void* d_out, int out_size, void* d_ws, size_t ws_size,
                              hipStream_t stream)
{
    const float* emissions = (const float*)d_in[0];
    const int*   tags      = (const int*)d_in[1];
    const int*   lengths   = (const int*)d_in[2];
    const float* start_tr  = (const float*)d_in[3];
    const float* end_tr    = (const float*)d_in[4];
    const float* trans     = (const float*)d_in[5];
    float* out = (float*)d_out;

    hipMemsetAsync(out, 0, sizeof(float), stream);

    crf_fused<<<NGROUP + NUMER_BLOCKS, 64, 0, stream>>>(
        emissions, tags, lengths, start_tr, end_tr, trans, out);
}